// Round 6
// baseline (1350.506 us; speedup 1.0000x reference)
//
#include <hip/hip_runtime.h>
#include <hip/hip_bf16.h>

#define NB 4
#define NS 1024
#define NIN 6
#define ND 512
#define NH 8
#define NLAYERS 4
#define NF 2048
#define NDK 64
#define LN_EPS 1e-5f

typedef unsigned short u16;
typedef __attribute__((ext_vector_type(4))) unsigned short u16x4;
typedef __attribute__((ext_vector_type(8))) short s16x8;     // 8 bf16 (4 VGPRs)
typedef __attribute__((ext_vector_type(4))) float f32x4;
typedef __attribute__((ext_vector_type(4))) unsigned int u32x4;

#define MFMA_BF16(A, B, C) __builtin_amdgcn_mfma_f32_16x16x32_bf16(A, B, C, 0, 0, 0)

#define GLOAD_LDS16(gsrc, ldst)                                                  \
    __builtin_amdgcn_global_load_lds(                                            \
        (const __attribute__((address_space(1))) void*)(gsrc),                   \
        (__attribute__((address_space(3))) void*)(ldst), 16, 0, 0)

// native bf16 RNE convert -> compiler emits v_cvt_pk_bf16_f32
__device__ inline u16 f2bf(float f) {
    __bf16 h = (__bf16)f;
    return __builtin_bit_cast(u16, h);
}
__device__ inline float bf2f(u16 v) {
    unsigned int u = (unsigned int)v << 16;
    return __builtin_bit_cast(float, u);
}

// ---------------- weight prep: W[K,N] f32 -> Wt[N,K] bf16 (batched via z) ------
__global__ __launch_bounds__(256) void transpose_kernel(
    const float* __restrict__ src, u16* __restrict__ dst, int K, int N) {
    __shared__ u16 t[64][72];
    const int tid = threadIdx.x;
    src += (size_t)blockIdx.z * K * N;
    dst += (size_t)blockIdx.z * K * N;
    const int n0 = blockIdx.x * 64, k0 = blockIdx.y * 64;
    {
        int r = tid >> 2, cq = (tid & 3) * 16;
        const float* sp = src + (size_t)(k0 + r) * N + n0 + cq;
#pragma unroll
        for (int q = 0; q < 4; ++q) {
            float4 v = *reinterpret_cast<const float4*>(sp + q * 4);
            t[r][cq + q * 4 + 0] = f2bf(v.x);
            t[r][cq + q * 4 + 1] = f2bf(v.y);
            t[r][cq + q * 4 + 2] = f2bf(v.z);
            t[r][cq + q * 4 + 3] = f2bf(v.w);
        }
    }
    __syncthreads();
    {
        int rn = tid >> 2, cq = (tid & 3) * 16;
        s16x8 o0, o1;
#pragma unroll
        for (int j = 0; j < 8; ++j) o0[j] = (short)t[cq + j][rn];
#pragma unroll
        for (int j = 0; j < 8; ++j) o1[j] = (short)t[cq + 8 + j][rn];
        u16* dp = dst + (size_t)(n0 + rn) * K + k0 + cq;
        *reinterpret_cast<s16x8*>(dp) = o0;
        *reinterpret_cast<s16x8*>(dp + 8) = o1;
    }
}

// ---------------- input projection: out = x @ W + b + pe (f32 + bf16 mirror) ---
__global__ __launch_bounds__(256) void in_proj_kernel(
    const float* __restrict__ x, const float* __restrict__ W,
    const float* __restrict__ bias, const float* __restrict__ pe,
    float* __restrict__ out, u16* __restrict__ outb) {
    int idx = blockIdx.x * 256 + threadIdx.x;      // over B*S*D
    int d = idx & (ND - 1);
    int bs = idx / ND;
    int s = bs & (NS - 1);
    const float* xr = x + (size_t)bs * NIN;
    float acc = bias[d] + pe[(size_t)s * ND + d];
#pragma unroll
    for (int i = 0; i < NIN; ++i) acc += xr[i] * W[(size_t)i * ND + d];
    out[idx] = acc;
    outb[idx] = f2bf(acc);
}

// ---------------- shared bf16-MFMA GEMM core: 128 x BN tile, BK=64 -------------
template <int BN>
__device__ inline void gemm_core(const u16* __restrict__ A, const u16* __restrict__ Wt,
                                 int K, int bm, int bn, char* lds, int tid,
                                 f32x4 (&acc)[4][BN / 32]) {
    constexpr int NT = BN / 32;
    constexpr int ASZ = 128 * 128;
    constexpr int BSZ = BN * 128;
    const int wid = tid >> 6, lane = tid & 63;
    const int l15 = lane & 15, lhi = lane >> 4;
    const int wr = wid >> 1, wc = wid & 1;

    auto stage = [&](int buf, int k0) {
#pragma unroll
        for (int i = 0; i < 4; ++i) {
            int slot = (wid * 4 + i) * 64 + lane;
            int r = slot >> 3, p = slot & 7;
            const char* src = (const char*)(A + (size_t)(bm + r) * K + k0)
                              + ((p * 16) ^ ((r & 7) << 4));
            GLOAD_LDS16(src, lds + buf * ASZ + (wid * 4 + i) * 1024);
        }
#pragma unroll
        for (int i = 0; i < BN / 32; ++i) {
            int slot = (wid * (BN / 32) + i) * 64 + lane;
            int r = slot >> 3, p = slot & 7;
            const char* src = (const char*)(Wt + (size_t)(bn + r) * K + k0)
                              + ((p * 16) ^ ((r & 7) << 4));
            GLOAD_LDS16(src, lds + 2 * ASZ + buf * BSZ + (wid * (BN / 32) + i) * 1024);
        }
    };

#pragma unroll
    for (int mt = 0; mt < 4; ++mt)
#pragma unroll
        for (int nt = 0; nt < NT; ++nt) acc[mt][nt] = f32x4{0.f, 0.f, 0.f, 0.f};

    const int KT = K >> 6;
    stage(0, 0);
    __syncthreads();
    for (int t = 0; t < KT; ++t) {
        if (t + 1 < KT) stage((t + 1) & 1, (t + 1) << 6);
        const char* Ab = lds + (t & 1) * ASZ;
        const char* Bb = lds + 2 * ASZ + (t & 1) * BSZ;
#pragma unroll
        for (int sl = 0; sl < 2; ++sl) {
            s16x8 af[4];
#pragma unroll
            for (int mt = 0; mt < 4; ++mt) {
                int row = wr * 64 + mt * 16 + l15;
                af[mt] = *reinterpret_cast<const s16x8*>(
                    Ab + ((row * 128 + sl * 64 + lhi * 16) ^ ((row & 7) << 4)));
            }
            s16x8 bfr[NT];
#pragma unroll
            for (int nt = 0; nt < NT; ++nt) {
                int row = wc * (BN / 2) + nt * 16 + l15;
                bfr[nt] = *reinterpret_cast<const s16x8*>(
                    Bb + ((row * 128 + sl * 64 + lhi * 16) ^ ((row & 7) << 4)));
            }
#pragma unroll
            for (int mt = 0; mt < 4; ++mt)
#pragma unroll
                for (int nt = 0; nt < NT; ++nt)
                    acc[mt][nt] = MFMA_BF16(af[mt], bfr[nt], acc[mt][nt]);
        }
        __syncthreads();
    }
}

// ---------------- dual-stream GEMM: z selects stream -------------------------
// OMODE: 1 bf16 out + relu; 2 bf16 out
template <int OMODE, int BN>
__global__ __launch_bounds__(256) void bgemm2_kernel(
    const u16* __restrict__ a0, const u16* __restrict__ a1,
    const u16* __restrict__ wt0, const u16* __restrict__ wt1,
    const float* __restrict__ bias0, const float* __restrict__ bias1,
    u16* __restrict__ Cv, int M, int N, int K) {
    constexpr int NT = BN / 32;
    __shared__ char lds[2 * 128 * 128 + 2 * BN * 128];
    const int tid = threadIdx.x, z = blockIdx.z;
    const int bm = blockIdx.y * 128, bn = blockIdx.x * BN;
    const u16* A = z ? a1 : a0;
    const u16* Wt = z ? wt1 : wt0;
    const float* bias = z ? bias1 : bias0;

    f32x4 acc[4][NT];
    gemm_core<BN>(A, Wt, K, bm, bn, lds, tid, acc);

    const int wid = tid >> 6, lane = tid & 63;
    const int l15 = lane & 15, lhi = lane >> 4;
    const int wr = wid >> 1, wc = wid & 1;
    float bv[NT];
#pragma unroll
    for (int nt = 0; nt < NT; ++nt) bv[nt] = bias[bn + wc * (BN / 2) + nt * 16 + l15];

    u16* C = Cv + (size_t)z * M * N;
#pragma unroll
    for (int mt = 0; mt < 4; ++mt) {
        int m0 = bm + wr * 64 + mt * 16 + lhi * 4;
#pragma unroll
        for (int nt = 0; nt < NT; ++nt) {
            int n = bn + wc * (BN / 2) + nt * 16 + l15;
#pragma unroll
            for (int r = 0; r < 4; ++r) {
                float v = acc[mt][nt][r] + bv[nt];
                if (OMODE == 1) v = fmaxf(v, 0.f);
                C[(size_t)(m0 + r) * N + n] = f2bf(v);
            }
        }
    }
}

// ---------------- fused dual-stream QKV projection ---------------------------
// grid (3*8, 32, 2): proj = x>>3 (0=Q rowmajor, 1=K rowmajor, 2=V transposed)
__global__ __launch_bounds__(256) void bgemm_qkv_kernel(
    const u16* __restrict__ aq0, const u16* __restrict__ aq1,
    const u16* __restrict__ akv0, const u16* __restrict__ akv1,
    const u16* __restrict__ wt0, const u16* __restrict__ wt1,
    const float* __restrict__ bb0, const float* __restrict__ bb1,
    u16* __restrict__ Qo, u16* __restrict__ Ko, u16* __restrict__ Vto) {
    __shared__ char lds[2 * 128 * 128 + 2 * 64 * 128];
    const int tid = threadIdx.x, z = blockIdx.z;
    const int proj = blockIdx.x >> 3;
    const int bm = blockIdx.y * 128, bn = (blockIdx.x & 7) * 64;
    const int M = NB * NS;
    const u16* A = (proj == 0) ? (z ? aq1 : aq0) : (z ? akv1 : akv0);
    const u16* Wt = (z ? wt1 : wt0) + (size_t)proj * ND * ND;
    const float* bias = (z ? bb1 : bb0) + proj * ND;

    f32x4 acc[4][2];
    gemm_core<64>(A, Wt, ND, bm, bn, lds, tid, acc);

    const int wid = tid >> 6, lane = tid & 63;
    const int l15 = lane & 15, lhi = lane >> 4;
    const int wr = wid >> 1, wc = wid & 1;
    float bv[2];
#pragma unroll
    for (int nt = 0; nt < 2; ++nt) bv[nt] = bias[bn + wc * 32 + nt * 16 + l15];

    if (proj < 2) {
        u16* C = (proj ? Ko : Qo) + (size_t)z * M * ND;
#pragma unroll
        for (int mt = 0; mt < 4; ++mt) {
            int m0 = bm + wr * 64 + mt * 16 + lhi * 4;
#pragma unroll
            for (int nt = 0; nt < 2; ++nt) {
                int n = bn + wc * 32 + nt * 16 + l15;
#pragma unroll
                for (int r = 0; r < 4; ++r)
                    C[(size_t)(m0 + r) * ND + n] = f2bf(acc[mt][nt][r] + bv[nt]);
            }
        }
    } else {
        // Vt[((b'*NH + h)*NDK + dk)*NS + s], b' = z*4 + m0>>10
#pragma unroll
        for (int mt = 0; mt < 4; ++mt) {
            int m0 = bm + wr * 64 + mt * 16 + lhi * 4;
            int b = (z * M + m0) >> 10, s = m0 & (NS - 1);
#pragma unroll
            for (int nt = 0; nt < 2; ++nt) {
                int n = bn + wc * 32 + nt * 16 + l15;
                int h = n >> 6, dk = n & 63;
                u16x4 o = {f2bf(acc[mt][nt][0] + bv[nt]), f2bf(acc[mt][nt][1] + bv[nt]),
                           f2bf(acc[mt][nt][2] + bv[nt]), f2bf(acc[mt][nt][3] + bv[nt])};
                *reinterpret_cast<u16x4*>(Vto + ((size_t)((b * NH + h) * NDK + dk)) * NS + s) = o;
            }
        }
    }
}

// ---------------- dual-stream residual + LayerNorm (bf16 x, f32 residual) -----
__global__ __launch_bounds__(256) void ln2_kernel(
    const u16* __restrict__ x, const float* __restrict__ res,
    const float* __restrict__ g0, const float* __restrict__ g1,
    const float* __restrict__ be0, const float* __restrict__ be1,
    float* __restrict__ outf, u16* __restrict__ outb) {
    int row = blockIdx.x;                 // 0..8191, stream = row>>12
    const float* g = (row >> 12) ? g1 : g0;
    const float* be = (row >> 12) ? be1 : be0;
    int tid = threadIdx.x;
    unsigned int xp = *reinterpret_cast<const unsigned int*>(x + (size_t)row * ND + tid * 2);
    float2 rr = *reinterpret_cast<const float2*>(res + (size_t)row * ND + tid * 2);
    float v0 = bf2f((u16)(xp & 0xffffu)) + rr.x;
    float v1 = bf2f((u16)(xp >> 16)) + rr.y;
    float s = v0 + v1, sq = v0 * v0 + v1 * v1;
#pragma unroll
    for (int m = 1; m < 64; m <<= 1) { s += __shfl_xor(s, m); sq += __shfl_xor(sq, m); }
    __shared__ float ls[4], lq[4];
    int wid = tid >> 6, lane = tid & 63;
    if (lane == 0) { ls[wid] = s; lq[wid] = sq; }
    __syncthreads();
    s = ls[0] + ls[1] + ls[2] + ls[3];
    sq = lq[0] + lq[1] + lq[2] + lq[3];
    float mean = s * (1.f / ND);
    float var = sq * (1.f / ND) - mean * mean;
    float rstd = rsqrtf(var + LN_EPS);
    float2 gg = *reinterpret_cast<const float2*>(g + tid * 2);
    float2 bb = *reinterpret_cast<const float2*>(be + tid * 2);
    float o0 = (v0 - mean) * rstd * gg.x + bb.x;
    float o1 = (v1 - mean) * rstd * gg.y + bb.y;
    float2 of = {o0, o1};
    *reinterpret_cast<float2*>(outf + (size_t)row * ND + tid * 2) = of;
    unsigned int ob = (unsigned int)f2bf(o0) | ((unsigned int)f2bf(o1) << 16);
    *reinterpret_cast<unsigned int*>(outb + (size_t)row * ND + tid * 2) = ob;
}

// ---------------- flash attention, bf16 MFMA, swapped-QK^T softmax ------------
// Q,K bf16 [8,S,D]; Vt bf16 [8*H,DK,S]; O bf16 [8,S,D]; grid (S/64, 64)
// KVBLK=128. global_load_lds staging: linear LDS dest, inverse-swizzled source.
__global__ __launch_bounds__(256) void attn_kernel(
    const u16* __restrict__ Qb, const u16* __restrict__ Kb,
    const u16* __restrict__ Vtb, u16* __restrict__ O) {
    __shared__ u16 Ks[128 * 64];       // [kv][d] swizzled, 16 KB
    __shared__ u16 Vts[64 * 128];      // [d][kv] swizzled, 16 KB
    __shared__ u16 Ps[4][16 * 128];    // per-wave P [q][kv] swizzled, 16 KB

    const int tid = threadIdx.x;
    const int w = tid >> 6, lane = tid & 63;
    const int l15 = lane & 15, lhi = lane >> 4;
    const int bh = blockIdx.y;
    const int b = bh >> 3, h = bh & 7;
    const int qb = blockIdx.x * 64 + w * 16;
    const float c1 = 0.18033688011f;   // 0.125 * log2(e)

    s16x8 qf[2];
    {
        const u16* qp = Qb + ((size_t)(b * NS) + qb + l15) * ND + h * NDK + lhi * 8;
        qf[0] = *reinterpret_cast<const s16x8*>(qp);
        qf[1] = *reinterpret_cast<const s16x8*>(qp + 32);
    }

    f32x4 o[4] = {f32x4{0.f, 0.f, 0.f, 0.f}, f32x4{0.f, 0.f, 0.f, 0.f},
                  f32x4{0.f, 0.f, 0.f, 0.f}, f32x4{0.f, 0.f, 0.f, 0.f}};
    float m = -1e30f;       // running max (raw-score domain) for q-row = l15
    float lsum = 0.f;

    const u16* Kbase = Kb + ((size_t)(b * NS)) * ND + h * NDK;
    const u16* Vbase = Vtb + ((size_t)bh * NDK) * NS;

    for (int c = 0; c < NS / 128; ++c) {
        const int kv0 = c * 128;
        __syncthreads();
        // ---- stage via global_load_lds (wave-uniform dest + lane*16) ----
#pragma unroll
        for (int i = 0; i < 4; ++i) {
            int slot = (w * 4 + i) * 64 + lane;
            {   // K: dest byte slot*16 -> row r = slot>>3, 16B-unit p = slot&7
                int r = slot >> 3, p = slot & 7;
                const char* src = (const char*)(Kbase + (size_t)(kv0 + r) * ND)
                                  + ((p ^ (r & 7)) * 16);
                GLOAD_LDS16(src, (char*)Ks + (w * 4 + i) * 1024);
            }
            {   // V: dest byte slot*16 -> row r = slot>>4, 16B-unit p = slot&15
                int r = slot >> 4, p = slot & 15;
                const char* src = (const char*)(Vbase + (size_t)r * NS + kv0)
                                  + ((p ^ (r & 7)) * 16);
                GLOAD_LDS16(src, (char*)Vts + (w * 4 + i) * 1024);
            }
        }
        __syncthreads();

        // ---- S^T = K @ Q^T : sc[blk] holds S[kv=blk*16+lhi*4+r][q=l15] ----
        f32x4 sc[8];
#pragma unroll
        for (int blk = 0; blk < 8; ++blk) sc[blk] = f32x4{0.f, 0.f, 0.f, 0.f};
#pragma unroll
        for (int sl = 0; sl < 2; ++sl) {
#pragma unroll
            for (int blk = 0; blk < 8; ++blk) {
                int krow = blk * 16 + l15;
                s16x8 kf = *reinterpret_cast<const s16x8*>((char*)Ks +
                    ((krow * 128 + sl * 64 + lhi * 16) ^ ((krow & 7) << 4)));
                sc[blk] = MFMA_BF16(kf, qf[sl], sc[blk]);
            }
        }
        // ---- online softmax in exp2 domain: lane owns q-row l15 ----
        float mx = -1e30f;
#pragma unroll
        for (int blk = 0; blk < 8; ++blk)
#pragma unroll
            for (int r = 0; r < 4; ++r) mx = fmaxf(mx, sc[blk][r]);
        mx = fmaxf(mx, __shfl_xor(mx, 16));
        mx = fmaxf(mx, __shfl_xor(mx, 32));
        float mn = fmaxf(m, mx);
        float corr = exp2f((m - mn) * c1);
        m = mn;
        float d = mn * c1;
        float rs = 0.f;
#pragma unroll
        for (int blk = 0; blk < 8; ++blk) {
#pragma unroll
            for (int r = 0; r < 4; ++r) {
                float p = exp2f(fmaf(sc[blk][r], c1, -d));
                sc[blk][r] = p;
                rs += p;
            }
        }
        rs += __shfl_xor(rs, 16);
        rs += __shfl_xor(rs, 32);
        lsum = lsum * corr + rs;
        // ---- P -> bf16 -> per-wave LDS (packed 8B stores) ----
#pragma unroll
        for (int blk = 0; blk < 8; ++blk) {
            u16x4 pk = {f2bf(sc[blk][0]), f2bf(sc[blk][1]),
                        f2bf(sc[blk][2]), f2bf(sc[blk][3])};
            *reinterpret_cast<u16x4*>((char*)(Ps[w]) +
                ((l15 * 256 + blk * 32 + lhi * 8) ^ ((l15 & 7) << 4))) = pk;
        }
        // ---- rescale O (O rows q = lhi*4 + r -> fetch corr from lane l15==q) ----
        float cO[4];
#pragma unroll
        for (int r = 0; r < 4; ++r) cO[r] = __shfl(corr, lhi * 4 + r);
#pragma unroll
        for (int db = 0; db < 4; ++db)
#pragma unroll
            for (int r = 0; r < 4; ++r) o[db][r] *= cO[r];
        // ---- PV: A = P (row q=l15), B = V (col d=l15) ----
#pragma unroll
        for (int sl2 = 0; sl2 < 4; ++sl2) {
            s16x8 pf = *reinterpret_cast<const s16x8*>((char*)(Ps[w]) +
                ((l15 * 256 + sl2 * 64 + lhi * 16) ^ ((l15 & 7) << 4)));
#pragma unroll
            for (int db = 0; db < 4; ++db) {
                int vr = db * 16 + l15;
                s16x8 vf = *reinterpret_cast<const s16x8*>((char*)Vts +
                    ((vr * 256 + sl2 * 64 + lhi * 16) ^ ((vr & 7) << 4)));
                o[db] = MFMA_BF16(pf, vf, o[db]);
            }
        }
    }
    float lsO[4];
#pragma unroll
    for (int r = 0; r < 4; ++r) lsO[r] = __shfl(lsum, lhi * 4 + r);
#pragma unroll
    for (int db = 0; db < 4; ++db) {
#pragma unroll
        for (int r = 0; r < 4; ++r) {
            int q = qb + lhi * 4 + r;
            O[((size_t)(b * NS) + q) * ND + h * NDK + db * 16 + l15] =
                f2bf(o[db][r] / lsO[r]);
        }
    }
}

// ---------------- mean pool (two-stage: partial sums + atomicAdd) -------------
// grid (4, 2, 8): b, half(left/right), seq-chunk of 128
__global__ __launch_bounds__(256) void pool2_kernel(
    const float* __restrict__ RES, float* __restrict__ fused) {
    const int b = blockIdx.x, half = blockIdx.y, sc = blockIdx.z;
    const size_t NTOK = (size_t)NB * NS * ND;
    const float* src = RES + (half ? NTOK : 0) + ((size_t)(b * NS + sc * 128)) * ND;
    const int tid = threadIdx.x;
#pragma unroll
    for (int cc = 0; cc < 2; ++cc) {
        int c = cc * 256 + tid;
        float s = 0.f;
        for (int r = 0; r < 128; ++r) s += src[(size_t)r * ND + c];
        atomicAdd(&fused[b * 1024 + half * 512 + c], s * (1.f / NS));
    }
}

// ---------------- heads: hidden = relu(fused @ w1 + b1) ----------------------
// grid (8, 8): x = b*2 + head, y = 64-col chunk
__global__ __launch_bounds__(256) void head_hidden_kernel(
    const float* __restrict__ fused,
    const float* __restrict__ w1a, const float* __restrict__ b1a,
    const float* __restrict__ w1b, const float* __restrict__ b1b,
    float* __restrict__ hid) {
    const int b = blockIdx.x >> 1, head = blockIdx.x & 1;
    const float* w1 = head ? w1b : w1a;
    const float* b1 = head ? b1b : b1a;
    const int tid = threadIdx.x;
    const int j = blockIdx.y * 64 + (tid & 63);
    const int kq = tid >> 6;
    const float* fr = fused + (size_t)b * (2 * ND);
    float p = 0.f;
    for (int k = kq * 256; k < kq * 256 + 256; ++k)
        p += fr[k] * w1[(size_t)k * ND + j];
    __shared__ float part[4][64];
    part[kq][tid & 63] = p;
    __syncthreads();
    if (tid < 64) {
        float v = part[0][tid] + part[1][tid] + part[2][tid] + part[3][tid] + b1[j];
        hid[(size_t)blockIdx.x * ND + j] = fmaxf(v, 0.f);
    }
}

// grid (8): x = b*2 + head; out[head*8 + b*2 + c]
__global__ __launch_bounds__(256) void head_out_kernel(
    const float* __restrict__ hid,
    const float* __restrict__ w2a, const float* __restrict__ b2a,
    const float* __restrict__ w2b, const float* __restrict__ b2b,
    float* __restrict__ out) {
    const int b = blockIdx.x >> 1, head = blockIdx.x & 1;
    const float* w2 = head ? w2b : w2a;
    const float* b2 = head ? b2b : b2a;
    const int tid = threadIdx.x;
    const float* hr = hid + (size_t)blockIdx.x * ND;
    float h0 = hr[tid], h1 = hr[tid + 256];
    float p0 = h0 * w2[tid * 2 + 0] + h1 * w2[(tid + 256) * 2 + 0];
    float p1 = h0 * w2[tid * 2 + 1] + h1 * w2[(tid + 256) * 2 + 1];
#pragma unroll
    for (int m = 1; m < 64; m <<= 1) { p0 += __shfl_xor(p0, m); p1 += __shfl_xor(p1, m); }
    __shared__ float r0s[4], r1s[4];
    int wid = tid >> 6, lane = tid & 63;
    if (lane == 0) { r0s[wid] = p0; r1s[wid] = p1; }
    __syncthreads();
    if (tid == 0) {
        out[head * 8 + b * 2 + 0] = r0s[0] + r0s[1] + r0s[2] + r0s[3] + b2[0];
        out[head * 8 + b * 2 + 1] = r1s[0] + r1s[1] + r1s[2] + r1s[3] + b2[1];
    }
}

extern "C" void kernel_launch(void* const* d_in, const int* in_sizes, int n_in,
                              void* d_out, int out_size, void* d_ws, size_t ws_size,
                              hipStream_t stream) {
    const float* left_wrist  = (const float*)d_in[0];
    const float* right_wrist = (const float*)d_in[1];
    const float* Wl = (const float*)d_in[2];
    const float* bl = (const float*)d_in[3];
    const float* Wr = (const float*)d_in[4];
    const float* br = (const float*)d_in[5];
    const float* pe = (const float*)d_in[6];
    const float* mha_w    = (const float*)d_in[7];   // [L,4,4,D,D]
    const float* mha_b    = (const float*)d_in[8];   // [L,4,4,D]
    const float* mha_ln_g = (const float*)d_in[9];   // [L,4,D]
    const float* mha_ln_b = (const float*)d_in[10];
    const float* ff_w1 = (const float*)d_in[11];     // [L,2,D,F]
    const float* ff_b1 = (const float*)d_in[12];     // [L,2,F]
    const float* ff_w2 = (const float*)d_in[13];     // [L,2,F,D]
    const float* ff_b2 = (const float*)d_in[14];     // [L,2,D]
    const float* ff_ln_g = (const float*)d_in[15];   // [L,2,D]
    const float* ff_ln_b = (const float*)d_in[16];
    const float* h1_w1 = (const float*)d_in[17];
    const float* h1_b1 = (const float*)d_in[18];
    const float* h1_w2 = (const float*)d_in[19];
    const float* h1_b2 = (const float*)d_in[20];
    const float* h2_w1 = (const float*)d_in[21];
    const float* h2_b1 = (const float*)d_in[22];
    const float* h2_w2 = (const float*)d_in[23];
    const float* h2_b2 = (const float*)d_in[24];
    float* out = (float*)d_out;

    const size_t NTOK = (size_t)NB * NS * ND;        // 2M elements per stream
    const int M = NB * NS;                            // 4096 rows per stream
    float* ws = (float*)d_ws;
    // f32 buffers
    float* RES   = ws;                  // residual stream [2,B,S,D]
    float* CRES  = RES + 2 * NTOK;      // cross-attn LN out (residual for self)
    float* TMPf  = CRES + 2 * NTOK;     // region reused as bf16 pre-LN buffer
    float* FUSED = TMPf + 2 * NTOK;     // 4096
    float* HID   = FUSED + NB * 2 * ND; // 8 x 512
    u16* TMPbf = (u16*)TMPf;
    // bf16 buffers
    u16* Xbf  = (u16*)(HID + 8 * ND);   // current stream bf16 [2,B,S,D]
    u16* CXbf = Xbf + 2 * NTOK;
    u16* Qbf  = CXbf + 2 * NTOK;
    u16* Kbf  = Qbf + 2 * NTOK;
    u16* Vtbf = Kbf + 2 * NTOK;
    u16* CTbf = Vtbf + 2 * NTOK;
    u16* Hh   = Qbf;                    // FFN hidden aliases Q/K/Vt/CT (dead then)
    u16* WtM  = CTbf + 2 * NTOK;        // 64 x [512,512]
    u16* WtF1 = WtM + (size_t)64 * ND * ND;
    u16* WtF2 = WtF1 + (size_t)8 * ND * NF;

    const size_t DD = (size_t)ND * ND;

    // ---- weight prep ----
    transpose_kernel<<<dim3(ND / 64, ND / 64, 64), 256, 0, stream>>>(mha_w, WtM, ND, ND);
    transpose_kernel<<<dim3(NF / 64, ND / 64, 8), 256, 0, stream>>>(ff_w1, WtF1, ND, NF);
    transpose_kernel<<<dim3(ND / 64, NF / 64, 8), 256, 0, stream>>>(ff_w2, WtF2, NF, ND);

    in_proj_kernel<<<(NB * NS * ND) / 256, 256, 0, stream>>>(left_wrist, Wl, bl, pe, RES, Xbf);
    in_proj_kernel<<<(NB * NS * ND) / 256, 256, 0, stream>>>(right_wrist, Wr, br, pe,
                                                             RES + NTOK, Xbf + NTOK);

    for (int l = 0; l < NLAYERS; ++l) {
        const u16* wt0 = WtM + ((size_t)l * 4 + 0) * 4 * DD;
        const u16* wt1 = WtM + ((size_t)l * 4 + 1) * 4 * DD;
        const u16* wt2 = WtM + ((size_t)l * 4 + 2) * 4 * DD;
        const u16* wt3 = WtM + ((size_t)l * 4 + 3) * 4 * DD;
        const float* bb0 = mha_b + ((size_t)l * 4 + 0) * 4 * ND;
        const float* bb1 = mha_b + ((size_t)l * 4 + 1) * 4 * ND;
        const float* bb2 = mha_b + ((size_t)l * 4 + 2) * 4 * ND;
        const float* bb3 = mha_b + ((size_t)l * 4 + 3) * 4 * ND;

        // ---- cross attention (left queries right, right queries left) ----
        bgemm_qkv_kernel<<<dim3(24, 32, 2), 256, 0, stream>>>(
            Xbf, Xbf + NTOK, Xbf + NTOK, Xbf, wt0, wt1, bb0, bb1, Qbf, Kbf, Vtbf);
        attn_kernel<<<dim3(NS / 64, 2 * NB * NH), 256, 0, stream>>>(Qbf, Kbf, Vtbf, CTbf);
        bgemm2_kernel<2, 64><<<dim3(8, 32, 2), 256, 0, stream>>>(
            CTbf, CTbf + NTOK, wt0 + 3 * DD, wt1 + 3 * DD, bb0 + 3 * ND, bb1 + 3 * ND,
            TMPbf, M, ND, ND);
        ln2_kernel<<<2 * M, 256, 0, stream>>>(
            TMPbf, RES, mha_ln_g + ((size_t)l * 4 + 0) * ND, mha_ln_g + ((size_t)l * 4 + 1) * ND,
            mha_ln_b + ((size_t)l * 4 + 0) * ND, mha_ln_b + ((size_t)l * 4 + 1) * ND,
            CRES, CXbf);

        // ---- self attention ----
        bgemm_qkv_kernel<<<dim3(24, 32, 2), 256, 0, stream>>>(
            CXbf, CXbf + NTOK, CXbf, CXbf + NTOK, wt2, wt3, bb2, bb3, Qbf, Kbf, Vtbf);
        attn_kernel<<<dim3(NS / 64, 2 * NB * NH), 256, 0, stream>>>(Qbf, Kbf, Vtbf, CTbf);
        bgemm2_kernel<2, 64><<<dim3(8, 32, 2), 256, 0, stream>>>(
            CTbf, CTbf + NTOK, wt2 + 3 * DD, wt3 + 3 * DD, bb2 + 3 * ND, bb3 + 3 * ND,
            TMPbf, M, ND, ND);
        ln2_kernel<<<2 * M, 256, 0, stream>>>(
            TMPbf, CRES, mha_ln_g + ((size_t)l * 4 + 2) * ND, mha_ln_g + ((size_t)l * 4 + 3) * ND,
            mha_ln_b + ((size_t)l * 4 + 2) * ND, mha_ln_b + ((size_t)l * 4 + 3) * ND,
            RES, Xbf);

        // ---- FFN (both channels batched) ----
        bgemm2_kernel<1, 128><<<dim3(16, 32, 2), 256, 0, stream>>>(
            Xbf, Xbf + NTOK, WtF1 + ((size_t)l * 2 + 0) * ND * NF, WtF1 + ((size_t)l * 2 + 1) * ND * NF,
            ff_b1 + ((size_t)l * 2 + 0) * NF, ff_b1 + ((size_t)l * 2 + 1) * NF,
            Hh, M, NF, ND);
        bgemm2_kernel<2, 64><<<dim3(8, 32, 2), 256, 0, stream>>>(
            Hh, Hh + (size_t)M * NF, WtF2 + ((size_t)l * 2 + 0) * NF * ND, WtF2 + ((size_t)l * 2 + 1) * NF * ND,
            ff_b2 + ((size_t)l * 2 + 0) * ND, ff_b2 + ((size_t)l * 2 + 1) * ND,
            TMPbf, M, ND, NF);
        ln2_kernel<<<2 * M, 256, 0, stream>>>(
            TMPbf, RES, ff_ln_g + ((size_t)l * 2 + 0) * ND, ff_ln_g + ((size_t)l * 2 + 1) * ND,
            ff_ln_b + ((size_t)l * 2 + 0) * ND, ff_ln_b + ((size_t)l * 2 + 1) * ND,
            RES, Xbf);
    }

    hipMemsetAsync(FUSED, 0, NB * 2 * ND * sizeof(float), stream);
    pool2_kernel<<<dim3(NB, 2, 8), 256, 0, stream>>>(RES, FUSED);
    head_hidden_kernel<<<dim3(8, 8), 256, 0, stream>>>(FUSED, h1_w1, h1_b1, h2_w1, h2_b1, HID);
    head_out_kernel<<<8, 256, 0, stream>>>(HID, h1_w2, h1_b2, h2_w2, h2_b2, out);
}

// Round 8
// 1320.082 us; speedup vs baseline: 1.0230x; 1.0230x over previous
//
#include <hip/hip_runtime.h>
#include <hip/hip_bf16.h>

#define NB 4
#define NS 1024
#define NIN 6
#define ND 512
#define NH 8
#define NLAYERS 4
#define NF 2048
#define NDK 64
#define LN_EPS 1e-5f

typedef unsigned short u16;
typedef __attribute__((ext_vector_type(4))) unsigned short u16x4;
typedef __attribute__((ext_vector_type(8))) short s16x8;     // 8 bf16 (4 VGPRs)
typedef __attribute__((ext_vector_type(4))) float f32x4;
typedef __attribute__((ext_vector_type(4))) unsigned int u32x4;

#define MFMA_BF16(A, B, C) __builtin_amdgcn_mfma_f32_16x16x32_bf16(A, B, C, 0, 0, 0)

#define GLOAD_LDS16(gsrc, ldst)                                                  \
    __builtin_amdgcn_global_load_lds(                                            \
        (const __attribute__((address_space(1))) void*)(gsrc),                   \
        (__attribute__((address_space(3))) void*)(ldst), 16, 0, 0)

// native bf16 RNE convert -> compiler emits v_cvt_pk_bf16_f32
__device__ inline u16 f2bf(float f) {
    __bf16 h = (__bf16)f;
    return __builtin_bit_cast(u16, h);
}
__device__ inline float bf2f(u16 v) {
    unsigned int u = (unsigned int)v << 16;
    return __builtin_bit_cast(float, u);
}

// ---------------- weight prep: W[K,N] f32 -> Wt[N,K] bf16 (batched via z) ------
__global__ __launch_bounds__(256) void transpose_kernel(
    const float* __restrict__ src, u16* __restrict__ dst, int K, int N) {
    __shared__ u16 t[64][72];
    const int tid = threadIdx.x;
    src += (size_t)blockIdx.z * K * N;
    dst += (size_t)blockIdx.z * K * N;
    const int n0 = blockIdx.x * 64, k0 = blockIdx.y * 64;
    {
        int r = tid >> 2, cq = (tid & 3) * 16;
        const float* sp = src + (size_t)(k0 + r) * N + n0 + cq;
#pragma unroll
        for (int q = 0; q < 4; ++q) {
            float4 v = *reinterpret_cast<const float4*>(sp + q * 4);
            t[r][cq + q * 4 + 0] = f2bf(v.x);
            t[r][cq + q * 4 + 1] = f2bf(v.y);
            t[r][cq + q * 4 + 2] = f2bf(v.z);
            t[r][cq + q * 4 + 3] = f2bf(v.w);
        }
    }
    __syncthreads();
    {
        int rn = tid >> 2, cq = (tid & 3) * 16;
        s16x8 o0, o1;
#pragma unroll
        for (int j = 0; j < 8; ++j) o0[j] = (short)t[cq + j][rn];
#pragma unroll
        for (int j = 0; j < 8; ++j) o1[j] = (short)t[cq + 8 + j][rn];
        u16* dp = dst + (size_t)(n0 + rn) * K + k0 + cq;
        *reinterpret_cast<s16x8*>(dp) = o0;
        *reinterpret_cast<s16x8*>(dp + 8) = o1;
    }
}

// ---------------- input projection: out = x @ W + b + pe (f32 + bf16 mirror) ---
__global__ __launch_bounds__(256) void in_proj_kernel(
    const float* __restrict__ x, const float* __restrict__ W,
    const float* __restrict__ bias, const float* __restrict__ pe,
    float* __restrict__ out, u16* __restrict__ outb) {
    int idx = blockIdx.x * 256 + threadIdx.x;      // over B*S*D
    int d = idx & (ND - 1);
    int bs = idx / ND;
    int s = bs & (NS - 1);
    const float* xr = x + (size_t)bs * NIN;
    float acc = bias[d] + pe[(size_t)s * ND + d];
#pragma unroll
    for (int i = 0; i < NIN; ++i) acc += xr[i] * W[(size_t)i * ND + d];
    out[idx] = acc;
    outb[idx] = f2bf(acc);
}

// ---------------- shared bf16-MFMA GEMM core: 128 x BN tile, BK=64 -------------
template <int BN>
__device__ inline void gemm_core(const u16* __restrict__ A, const u16* __restrict__ Wt,
                                 int K, int bm, int bn, char* lds, int tid,
                                 f32x4 (&acc)[4][BN / 32]) {
    constexpr int NT = BN / 32;
    constexpr int ASZ = 128 * 128;
    constexpr int BSZ = BN * 128;
    const int wid = tid >> 6, lane = tid & 63;
    const int l15 = lane & 15, lhi = lane >> 4;
    const int wr = wid >> 1, wc = wid & 1;

    auto stage = [&](int buf, int k0) {
#pragma unroll
        for (int i = 0; i < 4; ++i) {
            int slot = (wid * 4 + i) * 64 + lane;
            int r = slot >> 3, p = slot & 7;
            const char* src = (const char*)(A + (size_t)(bm + r) * K + k0)
                              + ((p * 16) ^ ((r & 7) << 4));
            GLOAD_LDS16(src, lds + buf * ASZ + (wid * 4 + i) * 1024);
        }
#pragma unroll
        for (int i = 0; i < BN / 32; ++i) {
            int slot = (wid * (BN / 32) + i) * 64 + lane;
            int r = slot >> 3, p = slot & 7;
            const char* src = (const char*)(Wt + (size_t)(bn + r) * K + k0)
                              + ((p * 16) ^ ((r & 7) << 4));
            GLOAD_LDS16(src, lds + 2 * ASZ + buf * BSZ + (wid * (BN / 32) + i) * 1024);
        }
    };

#pragma unroll
    for (int mt = 0; mt < 4; ++mt)
#pragma unroll
        for (int nt = 0; nt < NT; ++nt) acc[mt][nt] = f32x4{0.f, 0.f, 0.f, 0.f};

    const int KT = K >> 6;
    stage(0, 0);
    __syncthreads();
    for (int t = 0; t < KT; ++t) {
        if (t + 1 < KT) stage((t + 1) & 1, (t + 1) << 6);
        const char* Ab = lds + (t & 1) * ASZ;
        const char* Bb = lds + 2 * ASZ + (t & 1) * BSZ;
#pragma unroll
        for (int sl = 0; sl < 2; ++sl) {
            s16x8 af[4];
#pragma unroll
            for (int mt = 0; mt < 4; ++mt) {
                int row = wr * 64 + mt * 16 + l15;
                af[mt] = *reinterpret_cast<const s16x8*>(
                    Ab + ((row * 128 + sl * 64 + lhi * 16) ^ ((row & 7) << 4)));
            }
            s16x8 bfr[NT];
#pragma unroll
            for (int nt = 0; nt < NT; ++nt) {
                int row = wc * (BN / 2) + nt * 16 + l15;
                bfr[nt] = *reinterpret_cast<const s16x8*>(
                    Bb + ((row * 128 + sl * 64 + lhi * 16) ^ ((row & 7) << 4)));
            }
#pragma unroll
            for (int mt = 0; mt < 4; ++mt)
#pragma unroll
                for (int nt = 0; nt < NT; ++nt)
                    acc[mt][nt] = MFMA_BF16(af[mt], bfr[nt], acc[mt][nt]);
        }
        __syncthreads();
    }
}

// ---------------- dual-stream GEMM: z selects stream -------------------------
// OMODE: 1 bf16 out + relu; 2 bf16 out
template <int OMODE, int BN>
__global__ __launch_bounds__(256) void bgemm2_kernel(
    const u16* __restrict__ a0, const u16* __restrict__ a1,
    const u16* __restrict__ wt0, const u16* __restrict__ wt1,
    const float* __restrict__ bias0, const float* __restrict__ bias1,
    u16* __restrict__ Cv, int M, int N, int K) {
    constexpr int NT = BN / 32;
    __shared__ char lds[2 * 128 * 128 + 2 * BN * 128];
    const int tid = threadIdx.x, z = blockIdx.z;
    const int bm = blockIdx.y * 128, bn = blockIdx.x * BN;
    const u16* A = z ? a1 : a0;
    const u16* Wt = z ? wt1 : wt0;
    const float* bias = z ? bias1 : bias0;

    f32x4 acc[4][NT];
    gemm_core<BN>(A, Wt, K, bm, bn, lds, tid, acc);

    const int wid = tid >> 6, lane = tid & 63;
    const int l15 = lane & 15, lhi = lane >> 4;
    const int wr = wid >> 1, wc = wid & 1;
    float bv[NT];
#pragma unroll
    for (int nt = 0; nt < NT; ++nt) bv[nt] = bias[bn + wc * (BN / 2) + nt * 16 + l15];

    u16* C = Cv + (size_t)z * M * N;
#pragma unroll
    for (int mt = 0; mt < 4; ++mt) {
        int m0 = bm + wr * 64 + mt * 16 + lhi * 4;
#pragma unroll
        for (int nt = 0; nt < NT; ++nt) {
            int n = bn + wc * (BN / 2) + nt * 16 + l15;
#pragma unroll
            for (int r = 0; r < 4; ++r) {
                float v = acc[mt][nt][r] + bv[nt];
                if (OMODE == 1) v = fmaxf(v, 0.f);
                C[(size_t)(m0 + r) * N + n] = f2bf(v);
            }
        }
    }
}

// ---------------- fused dual-stream QKV projection ---------------------------
// grid (3*8, 32, 2): proj = x>>3 (0=Q rowmajor, 1=K rowmajor, 2=V transposed)
__global__ __launch_bounds__(256) void bgemm_qkv_kernel(
    const u16* __restrict__ aq0, const u16* __restrict__ aq1,
    const u16* __restrict__ akv0, const u16* __restrict__ akv1,
    const u16* __restrict__ wt0, const u16* __restrict__ wt1,
    const float* __restrict__ bb0, const float* __restrict__ bb1,
    u16* __restrict__ Qo, u16* __restrict__ Ko, u16* __restrict__ Vto) {
    __shared__ char lds[2 * 128 * 128 + 2 * 64 * 128];
    const int tid = threadIdx.x, z = blockIdx.z;
    const int proj = blockIdx.x >> 3;
    const int bm = blockIdx.y * 128, bn = (blockIdx.x & 7) * 64;
    const int M = NB * NS;
    const u16* A = (proj == 0) ? (z ? aq1 : aq0) : (z ? akv1 : akv0);
    const u16* Wt = (z ? wt1 : wt0) + (size_t)proj * ND * ND;
    const float* bias = (z ? bb1 : bb0) + proj * ND;

    f32x4 acc[4][2];
    gemm_core<64>(A, Wt, ND, bm, bn, lds, tid, acc);

    const int wid = tid >> 6, lane = tid & 63;
    const int l15 = lane & 15, lhi = lane >> 4;
    const int wr = wid >> 1, wc = wid & 1;
    float bv[2];
#pragma unroll
    for (int nt = 0; nt < 2; ++nt) bv[nt] = bias[bn + wc * 32 + nt * 16 + l15];

    if (proj < 2) {
        u16* C = (proj ? Ko : Qo) + (size_t)z * M * ND;
#pragma unroll
        for (int mt = 0; mt < 4; ++mt) {
            int m0 = bm + wr * 64 + mt * 16 + lhi * 4;
#pragma unroll
            for (int nt = 0; nt < 2; ++nt) {
                int n = bn + wc * 32 + nt * 16 + l15;
#pragma unroll
                for (int r = 0; r < 4; ++r)
                    C[(size_t)(m0 + r) * ND + n] = f2bf(acc[mt][nt][r] + bv[nt]);
            }
        }
    } else {
        // Vt[((b'*NH + h)*NDK + dk)*NS + s], b' = z*4 + m0>>10
#pragma unroll
        for (int mt = 0; mt < 4; ++mt) {
            int m0 = bm + wr * 64 + mt * 16 + lhi * 4;
            int b = (z * M + m0) >> 10, s = m0 & (NS - 1);
#pragma unroll
            for (int nt = 0; nt < 2; ++nt) {
                int n = bn + wc * 32 + nt * 16 + l15;
                int h = n >> 6, dk = n & 63;
                u16x4 o = {f2bf(acc[mt][nt][0] + bv[nt]), f2bf(acc[mt][nt][1] + bv[nt]),
                           f2bf(acc[mt][nt][2] + bv[nt]), f2bf(acc[mt][nt][3] + bv[nt])};
                *reinterpret_cast<u16x4*>(Vto + ((size_t)((b * NH + h) * NDK + dk)) * NS + s) = o;
            }
        }
    }
}

// ---------------- dual-stream residual + LayerNorm, wave-per-row --------------
// grid 2048, 4 waves/block, wave owns one row (8 elems/lane), no barriers
__global__ __launch_bounds__(256) void ln2_kernel(
    const u16* __restrict__ x, const float* __restrict__ res,
    const float* __restrict__ g0, const float* __restrict__ g1,
    const float* __restrict__ be0, const float* __restrict__ be1,
    float* __restrict__ outf, u16* __restrict__ outb) {
    const int wid = threadIdx.x >> 6, lane = threadIdx.x & 63;
    const int row = blockIdx.x * 4 + wid;   // 0..8191, stream = row>>12
    const float* g = (row >> 12) ? g1 : g0;
    const float* be = (row >> 12) ? be1 : be0;
    const int c0 = lane * 8;
    const size_t base = (size_t)row * ND + c0;

    u32x4 xp = *reinterpret_cast<const u32x4*>(x + base);
    float4 ra = *reinterpret_cast<const float4*>(res + base);
    float4 rb = *reinterpret_cast<const float4*>(res + base + 4);
    float v[8];
    v[0] = bf2f((u16)(xp[0] & 0xffffu)) + ra.x;
    v[1] = bf2f((u16)(xp[0] >> 16)) + ra.y;
    v[2] = bf2f((u16)(xp[1] & 0xffffu)) + ra.z;
    v[3] = bf2f((u16)(xp[1] >> 16)) + ra.w;
    v[4] = bf2f((u16)(xp[2] & 0xffffu)) + rb.x;
    v[5] = bf2f((u16)(xp[2] >> 16)) + rb.y;
    v[6] = bf2f((u16)(xp[3] & 0xffffu)) + rb.z;
    v[7] = bf2f((u16)(xp[3] >> 16)) + rb.w;

    float s = 0.f, sq = 0.f;
#pragma unroll
    for (int i = 0; i < 8; ++i) { s += v[i]; sq += v[i] * v[i]; }
#pragma unroll
    for (int m = 1; m < 64; m <<= 1) { s += __shfl_xor(s, m); sq += __shfl_xor(sq, m); }
    float mean = s * (1.f / ND);
    float var = sq * (1.f / ND) - mean * mean;
    float rstd = rsqrtf(var + LN_EPS);

    float4 ga = *reinterpret_cast<const float4*>(g + c0);
    float4 gb = *reinterpret_cast<const float4*>(g + c0 + 4);
    float4 ba = *reinterpret_cast<const float4*>(be + c0);
    float4 bb = *reinterpret_cast<const float4*>(be + c0 + 4);
    float gg[8] = {ga.x, ga.y, ga.z, ga.w, gb.x, gb.y, gb.z, gb.w};
    float bbv[8] = {ba.x, ba.y, ba.z, ba.w, bb.x, bb.y, bb.z, bb.w};
    float o[8];
#pragma unroll
    for (int i = 0; i < 8; ++i) o[i] = (v[i] - mean) * rstd * gg[i] + bbv[i];

    float4 oa = {o[0], o[1], o[2], o[3]};
    float4 ob = {o[4], o[5], o[6], o[7]};
    *reinterpret_cast<float4*>(outf + base) = oa;
    *reinterpret_cast<float4*>(outf + base + 4) = ob;
    u32x4 pk;
#pragma unroll
    for (int i = 0; i < 4; ++i)
        pk[i] = (unsigned int)f2bf(o[2 * i]) | ((unsigned int)f2bf(o[2 * i + 1]) << 16);
    *reinterpret_cast<u32x4*>(outb + base) = pk;
}

// ---------------- flash attention, bf16 MFMA, swapped-QK^T softmax ------------
// Q,K bf16 [8,S,D]; Vt bf16 [8*H,DK,S]; O bf16 [8,S,D]; grid (S/64, 64)
// KVBLK=128, half-PV (Ps = 2KB/wave), defer-max THR=8, 40KB LDS -> 4 blocks/CU
__global__ __launch_bounds__(256, 4) void attn_kernel(
    const u16* __restrict__ Qb, const u16* __restrict__ Kb,
    const u16* __restrict__ Vtb, u16* __restrict__ O) {
    __shared__ u16 Ks[128 * 64];       // [kv][d] swizzled, 16 KB
    __shared__ u16 Vts[64 * 128];      // [d][kv] swizzled, 16 KB
    __shared__ u16 Ps[4][16 * 64];     // per-wave P half [q][kv64] swizzled, 8 KB

    const int tid = threadIdx.x;
    const int w = tid >> 6, lane = tid & 63;
    const int l15 = lane & 15, lhi = lane >> 4;
    const int bh = blockIdx.y;
    const int b = bh >> 3, h = bh & 7;
    const int qb = blockIdx.x * 64 + w * 16;
    const float c1 = 0.18033688011f;   // 0.125 * log2(e)

    s16x8 qf[2];
    {
        const u16* qp = Qb + ((size_t)(b * NS) + qb + l15) * ND + h * NDK + lhi * 8;
        qf[0] = *reinterpret_cast<const s16x8*>(qp);
        qf[1] = *reinterpret_cast<const s16x8*>(qp + 32);
    }

    f32x4 o[4] = {f32x4{0.f, 0.f, 0.f, 0.f}, f32x4{0.f, 0.f, 0.f, 0.f},
                  f32x4{0.f, 0.f, 0.f, 0.f}, f32x4{0.f, 0.f, 0.f, 0.f}};
    float m = -1e30f;       // running max (raw-score domain) for q-row = l15
    float lsum = 0.f;

    const u16* Kbase = Kb + ((size_t)(b * NS)) * ND + h * NDK;
    const u16* Vbase = Vtb + ((size_t)bh * NDK) * NS;

    for (int c = 0; c < NS / 128; ++c) {
        const int kv0 = c * 128;
        __syncthreads();
        // ---- stage via global_load_lds (wave-uniform dest + lane*16) ----
#pragma unroll
        for (int i = 0; i < 4; ++i) {
            int slot = (w * 4 + i) * 64 + lane;
            {   // K: dest byte slot*16 -> row r = slot>>3, 16B-unit p = slot&7
                int r = slot >> 3, p = slot & 7;
                const char* src = (const char*)(Kbase + (size_t)(kv0 + r) * ND)
                                  + ((p ^ (r & 7)) * 16);
                GLOAD_LDS16(src, (char*)Ks + (w * 4 + i) * 1024);
            }
            {   // V: dest byte slot*16 -> row r = slot>>4, 16B-unit p = slot&15
                int r = slot >> 4, p = slot & 15;
                const char* src = (const char*)(Vbase + (size_t)r * NS + kv0)
                                  + ((p ^ (r & 7)) * 16);
                GLOAD_LDS16(src, (char*)Vts + (w * 4 + i) * 1024);
            }
        }
        __syncthreads();

        // ---- S^T = K @ Q^T : sc[blk] holds S[kv=blk*16+lhi*4+r][q=l15] ----
        f32x4 sc[8];
#pragma unroll
        for (int blk = 0; blk < 8; ++blk) sc[blk] = f32x4{0.f, 0.f, 0.f, 0.f};
#pragma unroll
        for (int sl = 0; sl < 2; ++sl) {
#pragma unroll
            for (int blk = 0; blk < 8; ++blk) {
                int krow = blk * 16 + l15;
                s16x8 kf = *reinterpret_cast<const s16x8*>((char*)Ks +
                    ((krow * 128 + sl * 64 + lhi * 16) ^ ((krow & 7) << 4)));
                sc[blk] = MFMA_BF16(kf, qf[sl], sc[blk]);
            }
        }
        // ---- online softmax in exp2 domain, defer-max THR=8 ----
        float mx = -1e30f;
#pragma unroll
        for (int blk = 0; blk < 8; ++blk)
#pragma unroll
            for (int r = 0; r < 4; ++r) mx = fmaxf(mx, sc[blk][r]);
        mx = fmaxf(mx, __shfl_xor(mx, 16));
        mx = fmaxf(mx, __shfl_xor(mx, 32));
        float mn = fmaxf(m, mx);
        if (__any((mn - m) * c1 > 8.f)) {   // some q-row grew beyond headroom
            float corr = exp2f((m - mn) * c1);
            m = mn;
            lsum *= corr;
            float cO[4];
#pragma unroll
            for (int r = 0; r < 4; ++r) cO[r] = __shfl(corr, lhi * 4 + r);
#pragma unroll
            for (int db = 0; db < 4; ++db)
#pragma unroll
                for (int r = 0; r < 4; ++r) o[db][r] *= cO[r];
        }
        float d = m * c1;
        float rs = 0.f;
#pragma unroll
        for (int blk = 0; blk < 8; ++blk) {
#pragma unroll
            for (int r = 0; r < 4; ++r) {
                float p = exp2f(fmaf(sc[blk][r], c1, -d));
                sc[blk][r] = p;
                rs += p;
            }
        }
        rs += __shfl_xor(rs, 16);
        rs += __shfl_xor(rs, 32);
        lsum += rs;

        // ---- PV in two kv-halves through the small per-wave P buffer ----
#pragma unroll
        for (int hh = 0; hh < 2; ++hh) {
#pragma unroll
            for (int bl = 0; bl < 4; ++bl) {
                int blk = hh * 4 + bl;
                u16x4 pk = {f2bf(sc[blk][0]), f2bf(sc[blk][1]),
                            f2bf(sc[blk][2]), f2bf(sc[blk][3])};
                *reinterpret_cast<u16x4*>((char*)(Ps[w]) +
                    ((l15 * 128 + bl * 32 + lhi * 8) ^ ((l15 & 7) << 4))) = pk;
            }
#pragma unroll
            for (int sl2 = 0; sl2 < 2; ++sl2) {
                s16x8 pf = *reinterpret_cast<const s16x8*>((char*)(Ps[w]) +
                    ((l15 * 128 + sl2 * 64 + lhi * 16) ^ ((l15 & 7) << 4)));
                int ss = hh * 2 + sl2;
#pragma unroll
                for (int db = 0; db < 4; ++db) {
                    int vr = db * 16 + l15;
                    s16x8 vf = *reinterpret_cast<const s16x8*>((char*)Vts +
                        ((vr * 256 + ss * 64 + lhi * 16) ^ ((vr & 7) << 4)));
                    o[db] = MFMA_BF16(pf, vf, o[db]);
                }
            }
        }
    }
    float lsO[4];
#pragma unroll
    for (int r = 0; r < 4; ++r) lsO[r] = __shfl(lsum, lhi * 4 + r);
#pragma unroll
    for (int db = 0; db < 4; ++db) {
#pragma unroll
        for (int r = 0; r < 4; ++r) {
            int q = qb + lhi * 4 + r;
            O[((size_t)(b * NS) + q) * ND + h * NDK + db * 16 + l15] =
                f2bf(o[db][r] / lsO[r]);
        }
    }
}

// ---------------- mean pool (two-stage: partial sums + atomicAdd) -------------
// grid (4, 2, 8): b, half(left/right), seq-chunk of 128
__global__ __launch_bounds__(256) void pool2_kernel(
    const float* __restrict__ RES, float* __restrict__ fused) {
    const int b = blockIdx.x, half = blockIdx.y, sc = blockIdx.z;
    const size_t NTOK = (size_t)NB * NS * ND;
    const float* src = RES + (half ? NTOK : 0) + ((size_t)(b * NS + sc * 128)) * ND;
    const int tid = threadIdx.x;
#pragma unroll
    for (int cc = 0; cc < 2; ++cc) {
        int c = cc * 256 + tid;
        float s = 0.f;
        for (int r = 0; r < 128; ++r) s += src[(size_t)r * ND + c];
        atomicAdd(&fused[b * 1024 + half * 512 + c], s * (1.f / NS));
    }
}

// ---------------- heads: hidden = relu(fused @ w1 + b1) ----------------------
// grid (8, 8): x = b*2 + head, y = 64-col chunk
__global__ __launch_bounds__(256) void head_hidden_kernel(
    const float* __restrict__ fused,
    const float* __restrict__ w1a, const float* __restrict__ b1a,
    const float* __restrict__ w1b, const float* __restrict__ b1b,
    float* __restrict__ hid) {
    const int b = blockIdx.x >> 1, head = blockIdx.x & 1;
    const float* w1 = head ? w1b : w1a;
    const float* b1 = head ? b1b : b1a;
    const int tid = threadIdx.x;
    const int j = blockIdx.y * 64 + (tid & 63);
    const int kq = tid >> 6;
    const float* fr = fused + (size_t)b * (2 * ND);
    float p = 0.f;
    for (int k = kq * 256; k < kq * 256 + 256; ++k)
        p += fr[k] * w1[(size_t)k * ND + j];
    __shared__ float part[4][64];
    part[kq][tid & 63] = p;
    __syncthreads();
    if (tid < 64) {
        float v = part[0][tid] + part[1][tid] + part[2][tid] + part[3][tid] + b1[j];
        hid[(size_t)blockIdx.x * ND + j] = fmaxf(v, 0.f);
    }
}

// grid (8): x = b*2 + head; out[head*8 + b*2 + c]
__global__ __launch_bounds__(256) void head_out_kernel(
    const float* __restrict__ hid,
    const float* __restrict__ w2a, const float* __restrict__ b2a,
    const float* __restrict__ w2b, const float* __restrict__ b2b,
    float* __restrict__ out) {
    const int b = blockIdx.x >> 1, head = blockIdx.x & 1;
    const float* w2 = head ? w2b : w2a;
    const float* b2 = head ? b2b : b2a;
    const int tid = threadIdx.x;
    const float* hr = hid + (size_t)blockIdx.x * ND;
    float h0 = hr[tid], h1 = hr[tid + 256];
    float p0 = h0 * w2[tid * 2 + 0] + h1 * w2[(tid + 256) * 2 + 0];
    float p1 = h0 * w2[tid * 2 + 1] + h1 * w2[(tid + 256) * 2 + 1];
#pragma unroll
    for (int m = 1; m < 64; m <<= 1) { p0 += __shfl_xor(p0, m); p1 += __shfl_xor(p1, m); }
    __shared__ float r0s[4], r1s[4];
    int wid = tid >> 6, lane = tid & 63;
    if (lane == 0) { r0s[wid] = p0; r1s[wid] = p1; }
    __syncthreads();
    if (tid == 0) {
        out[head * 8 + b * 2 + 0] = r0s[0] + r0s[1] + r0s[2] + r0s[3] + b2[0];
        out[head * 8 + b * 2 + 1] = r1s[0] + r1s[1] + r1s[2] + r1s[3] + b2[1];
    }
}

extern "C" void kernel_launch(void* const* d_in, const int* in_sizes, int n_in,
                              void* d_out, int out_size, void* d_ws, size_t ws_size,
                              hipStream_t stream) {
    const float* left_wrist  = (const float*)d_in[0];
    const float* right_wrist = (const float*)d_in[1];
    const float* Wl = (const float*)d_in[2];
    const float* bl = (const float*)d_in[3];
    const float* Wr = (const float*)d_in[4];
    const float* br = (const float*)d_in[5];
    const float* pe = (const float*)d_in[6];
    const float* mha_w    = (const float*)d_in[7];   // [L,4,4,D,D]
    const float* mha_b    = (const float*)d_in[8];   // [L,4,4,D]
    const float* mha_ln_g = (const float*)d_in[9];   // [L,4,D]
    const float* mha_ln_b = (const float*)d_in[10];
    const float* ff_w1 = (const float*)d_in[11];     // [L,2,D,F]
    const float* ff_b1 = (const float*)d_in[12];     // [L,2,F]
    const float* ff_w2 = (const float*)d_in[13];     // [L,2,F,D]
    const float* ff_b2 = (const float*)d_in[14];     // [L,2,D]
    const float* ff_ln_g = (const float*)d_in[15];   // [L,2,D]
    const float* ff_ln_b = (const float*)d_in[16];
    const float* h1_w1 = (const float*)d_in[17];
    const float* h1_b1 = (const float*)d_in[18];
    const float* h1_w2 = (const float*)d_in[19];
    const float* h1_b2 = (const float*)d_in[20];
    const float* h2_w1 = (const float*)d_in[21];
    const float* h2_b1 = (const float*)d_in[22];
    const float* h2_w2 = (const float*)d_in[23];
    const float* h2_b2 = (const float*)d_in[24];
    float* out = (float*)d_out;

    const size_t NTOK = (size_t)NB * NS * ND;        // 2M elements per stream
    const int M = NB * NS;                            // 4096 rows per stream
    float* ws = (float*)d_ws;
    // f32 buffers
    float* RES   = ws;                  // residual stream [2,B,S,D]
    float* CRES  = RES + 2 * NTOK;      // cross-attn LN out (residual for self)
    float* TMPf  = CRES + 2 * NTOK;     // region reused as bf16 pre-LN buffer
    float* FUSED = TMPf + 2 * NTOK;     // 4096
    float* HID   = FUSED + NB * 2 * ND; // 8 x 512
    u16* TMPbf = (u16*)TMPf;
    // bf16 buffers
    u16* Xbf  = (u16*)(HID + 8 * ND);   // current stream bf16 [2,B,S,D]
    u16* CXbf = Xbf + 2 * NTOK;
    u16* Qbf  = CXbf + 2 * NTOK;
    u16* Kbf  = Qbf + 2 * NTOK;
    u16* Vtbf = Kbf + 2 * NTOK;
    u16* CTbf = Vtbf + 2 * NTOK;
    u16* Hh   = Qbf;                    // FFN hidden aliases Q/K/Vt/CT (dead then)
    u16* WtM  = CTbf + 2 * NTOK;        // 64 x [512,512]
    u16* WtF1 = WtM + (size_t)64 * ND * ND;
    u16* WtF2 = WtF1 + (size_t)8 * ND * NF;

    const size_t DD = (size_t)ND * ND;

    // ---- weight prep ----
    transpose_kernel<<<dim3(ND / 64, ND / 64, 64), 256, 0, stream>>>(mha_w, WtM, ND, ND);
    transpose_kernel<<<dim3(NF / 64, ND / 64, 8), 256, 0, stream>>>(ff_w1, WtF1, ND, NF);
    transpose_kernel<<<dim3(ND / 64, NF / 64, 8), 256, 0, stream>>>(ff_w2, WtF2, NF, ND);

    in_proj_kernel<<<(NB * NS * ND) / 256, 256, 0, stream>>>(left_wrist, Wl, bl, pe, RES, Xbf);
    in_proj_kernel<<<(NB * NS * ND) / 256, 256, 0, stream>>>(right_wrist, Wr, br, pe,
                                                             RES + NTOK, Xbf + NTOK);

    for (int l = 0; l < NLAYERS; ++l) {
        const u16* wt0 = WtM + ((size_t)l * 4 + 0) * 4 * DD;
        const u16* wt1 = WtM + ((size_t)l * 4 + 1) * 4 * DD;
        const u16* wt2 = WtM + ((size_t)l * 4 + 2) * 4 * DD;
        const u16* wt3 = WtM + ((size_t)l * 4 + 3) * 4 * DD;
        const float* bb0 = mha_b + ((size_t)l * 4 + 0) * 4 * ND;
        const float* bb1 = mha_b + ((size_t)l * 4 + 1) * 4 * ND;
        const float* bb2 = mha_b + ((size_t)l * 4 + 2) * 4 * ND;
        const float* bb3 = mha_b + ((size_t)l * 4 + 3) * 4 * ND;

        // ---- cross attention (left queries right, right queries left) ----
        bgemm_qkv_kernel<<<dim3(24, 32, 2), 256, 0, stream>>>(
            Xbf, Xbf + NTOK, Xbf + NTOK, Xbf, wt0, wt1, bb0, bb1, Qbf, Kbf, Vtbf);
        attn_kernel<<<dim3(NS / 64, 2 * NB * NH), 256, 0, stream>>>(Qbf, Kbf, Vtbf, CTbf);
        bgemm2_kernel<2, 64><<<dim3(8, 32, 2), 256, 0, stream>>>(
            CTbf, CTbf + NTOK, wt0 + 3 * DD, wt1 + 3 * DD, bb0 + 3 * ND, bb1 + 3 * ND,
            TMPbf, M, ND, ND);
        ln2_kernel<<<2 * M / 4, 256, 0, stream>>>(
            TMPbf, RES, mha_ln_g + ((size_t)l * 4 + 0) * ND, mha_ln_g + ((size_t)l * 4 + 1) * ND,
            mha_ln_b + ((size_t)l * 4 + 0) * ND, mha_ln_b + ((size_t)l * 4 + 1) * ND,
            CRES, CXbf);

        // ---- self attention ----
        bgemm_qkv_kernel<<<dim3(24, 32, 2), 256, 0, stream>>>(
            CXbf, CXbf + NTOK, CXbf, CXbf + NTOK, wt2, wt3, bb2, bb3, Qbf, Kbf, Vtbf);
        attn_kernel<<<dim3(NS / 64, 2 * NB * NH), 256, 0, stream>>>(Qbf, Kbf, Vtbf, CTbf);
        bgemm2_kernel<2, 64><<<dim3(8, 32, 2), 256, 0, stream>>>(
            CTbf, CTbf + NTOK, wt2 + 3 * DD, wt3 + 3 * DD, bb2 + 3 * ND, bb3 + 3 * ND,
            TMPbf, M, ND, ND);
        ln2_kernel<<<2 * M / 4, 256, 0, stream>>>(
            TMPbf, CRES, mha_ln_g + ((size_t)l * 4 + 2) * ND, mha_ln_g + ((size_t)l * 4 + 3) * ND,
            mha_ln_b + ((size_t)l * 4 + 2) * ND, mha_ln_b + ((size_t)l * 4 + 3) * ND,
            RES, Xbf);

        // ---- FFN (both channels batched) ----
        bgemm2_kernel<1, 128><<<dim3(16, 32, 2), 256, 0, stream>>>(
            Xbf, Xbf + NTOK, WtF1 + ((size_t)l * 2 + 0) * ND * NF, WtF1 + ((size_t)l * 2 + 1) * ND * NF,
            ff_b1 + ((size_t)l * 2 + 0) * NF, ff_b1 + ((size_t)l * 2 + 1) * NF,
            Hh, M, NF, ND);
        bgemm2_kernel<2, 64><<<dim3(8, 32, 2), 256, 0, stream>>>(
            Hh, Hh + (size_t)M * NF, WtF2 + ((size_t)l * 2 + 0) * NF * ND, WtF2 + ((size_t)l * 2 + 1) * NF * ND,
            ff_b2 + ((size_t)l * 2 + 0) * ND, ff_b2 + ((size_t)l * 2 + 1) * ND,
            TMPbf, M, ND, NF);
        ln2_kernel<<<2 * M / 4, 256, 0, stream>>>(
            TMPbf, RES, ff_ln_g + ((size_t)l * 2 + 0) * ND, ff_ln_g + ((size_t)l * 2 + 1) * ND,
            ff_ln_b + ((size_t)l * 2 + 0) * ND, ff_ln_b + ((size_t)l * 2 + 1) * ND,
            RES, Xbf);
    }

    hipMemsetAsync(FUSED, 0, NB * 2 * ND * sizeof(float), stream);
    pool2_kernel<<<dim3(NB, 2, 8), 256, 0, stream>>>(RES, FUSED);
    head_hidden_kernel<<<dim3(8, 8), 256, 0, stream>>>(FUSED, h1_w1, h1_b1, h2_w1, h2_b1, HID);
    head_out_kernel<<<8, 256, 0, stream>>>(HID, h1_w2, h1_b2, h2_w2, h2_b2, out);
}